// Round 13
// baseline (298.956 us; speedup 1.0000x reference)
//
#include <hip/hip_runtime.h>
#include <math.h>

#define HDIM 512
#define LSEQ 2048
#define NH 8
#define DH 64
#define NEGBIG (-3.0e38f)

#define MODE_QDUAL  0
#define MODE_KV     1
#define MODE_VT     2
#define MODE_RE     3
#define MODE_B16RES 4
#define MODE_GELU   5

typedef short bf16x8 __attribute__((ext_vector_type(8)));
typedef float f32x4 __attribute__((ext_vector_type(4)));

__device__ __forceinline__ unsigned short f2b(float f) {
  union { float f; unsigned u; } x; x.f = f;
  unsigned r = x.u + 0x7FFF + ((x.u >> 16) & 1);
  return (unsigned short)(r >> 16);
}
__device__ __forceinline__ float b2f(unsigned short u) {
  union { unsigned u; float f; } x; x.u = ((unsigned)u) << 16;
  return x.f;
}

// async global->LDS, 16B per lane; LDS dest = wave-uniform base + lane*16
__device__ __forceinline__ void gl_lds16(const void* g, void* l) {
  __builtin_amdgcn_global_load_lds(
      (const __attribute__((address_space(1))) void*)g,
      (__attribute__((address_space(3))) void*)l, 16, 0, 0);
}

// ---------------------------------------------------------------------------
// Fused prep: z=0 convert x, z=1 convert pos_enc, z=2 convert/transpose weights
// ---------------------------------------------------------------------------
__global__ __launch_bounds__(256) void conv_all(
    const float* __restrict__ x, const float* __restrict__ pos,
    const float* __restrict__ Wq, const float* __restrict__ Wk,
    const float* __restrict__ Wv, const float* __restrict__ Wr,
    const float* __restrict__ Wc, const float* __restrict__ W1,
    const float* __restrict__ W2,
    unsigned short* __restrict__ xb, unsigned short* __restrict__ posb,
    unsigned short* __restrict__ wT)
{
  const int t = threadIdx.x;
  const int z = blockIdx.z;
  if (z == 0) {
    int idx = blockIdx.x * 256 + t;
    float4 v = ((const float4*)x)[idx];
    ushort4 o; o.x = f2b(v.x); o.y = f2b(v.y); o.z = f2b(v.z); o.w = f2b(v.w);
    ((ushort4*)xb)[idx] = o;
  } else if (z == 1) {
    int idx = blockIdx.x * 256 + t;
    if (idx < 262144) {
      float4 v = ((const float4*)pos)[idx];
      ushort4 o; o.x = f2b(v.x); o.y = f2b(v.y); o.z = f2b(v.z); o.w = f2b(v.w);
      ((ushort4*)posb)[idx] = o;
    }
  } else {
    if (blockIdx.x >= 448) return;
    const int widx = blockIdx.x >> 6;
    const int tile = blockIdx.x & 63;
    const float* src = (widx == 0) ? Wq : (widx == 1) ? Wk : (widx == 2) ? Wv :
                       (widx == 3) ? Wr : (widx == 4) ? Wc : (widx == 5) ? W1 : W2;
    unsigned short* dst = wT + (size_t)widx * 262144;
    if (widx < 4) {
      __shared__ float td[64][65];
      const int h0 = (tile >> 3) * 64;
      const int n  = tile & 7;
      #pragma unroll
      for (int it = 0; it < 4; ++it) {
        int row = it * 16 + (t >> 4), dc = (t & 15) * 4;
        float4 v = *(const float4*)(src + (size_t)n * 32768 + (size_t)(h0 + row) * 64 + dc);
        td[row][dc] = v.x; td[row][dc + 1] = v.y; td[row][dc + 2] = v.z; td[row][dc + 3] = v.w;
      }
      __syncthreads();
      #pragma unroll
      for (int it = 0; it < 4; ++it) {
        int d = it * 16 + (t >> 4), h4 = (t & 15) * 4;
        ushort4 o;
        o.x = f2b(td[h4 + 0][d]); o.y = f2b(td[h4 + 1][d]);
        o.z = f2b(td[h4 + 2][d]); o.w = f2b(td[h4 + 3][d]);
        *(ushort4*)(dst + (size_t)(n * 64 + d) * 512 + h0 + h4) = o;
      }
    } else {
      #pragma unroll
      for (int i = 0; i < 4; ++i) {
        int f4 = tile * 1024 + i * 256 + t;
        float4 v = ((const float4*)src)[f4];
        ushort4 o; o.x = f2b(v.x); o.y = f2b(v.y); o.z = f2b(v.z); o.w = f2b(v.w);
        ((ushort4*)dst)[f4] = o;
      }
    }
  }
}

// ---------------------------------------------------------------------------
// MFMA GEMM core, 64x64 tile, R13: BK=128 (4 drains instead of 8; 32 KB LDS,
// still 4 blocks/CU). 16-chunk XOR swizzle: phys_chunk = log_chunk ^ (row&15)
// -> b128 frag reads land 2 lanes/word-group = conflict-free.
// ---------------------------------------------------------------------------
__device__ __forceinline__ void gemm_core(
    const unsigned short* __restrict__ A, const unsigned short* __restrict__ BT,
    const float* __restrict__ bias, const float* __restrict__ cb2,
    const float* __restrict__ pb2, const float* __restrict__ resf,
    const unsigned short* __restrict__ res16,
    void* __restrict__ C1v, unsigned short* __restrict__ C2, int mode,
    int bx, int by, char* SMEM)
{
  unsigned short* As = (unsigned short*)SMEM;            // [64][128] 16 KB
  unsigned short* Bs = (unsigned short*)(SMEM + 16384);  // [64][128] 16 KB

  const int t = threadIdx.x;
  const int w = t >> 6, lane = t & 63;
  const int l15 = lane & 15, quad = lane >> 4;
  const int r0 = by * 64;
  const int c0 = bx * 64;
  const int wm = (w >> 1) * 32, wc = (w & 1) * 32;

  f32x4 acc[2][2];
  #pragma unroll
  for (int sr = 0; sr < 2; ++sr)
    #pragma unroll
    for (int sc = 0; sc < 2; ++sc) acc[sr][sc] = (f32x4){0.f, 0.f, 0.f, 0.f};

  const int lrow = lane >> 4;     // row within a 4-row staging slab
  const int lch  = lane & 15;     // physical 16B chunk this lane writes

  for (int k0 = 0; k0 < 512; k0 += 128) {
    __syncthreads();
    #pragma unroll
    for (int i = 0; i < 4; ++i) {
      int rowb = w * 16 + i * 4;            // wave-uniform slab base
      int row  = rowb + lrow;
      int c    = lch ^ (row & 15);          // logical chunk for this lane
      gl_lds16(A  + (size_t)(r0 + row) * 512 + k0 + c * 8, As + rowb * 128);
      gl_lds16(BT + (size_t)(c0 + row) * 512 + k0 + c * 8, Bs + rowb * 128);
    }
    __syncthreads();

    #pragma unroll
    for (int kk = 0; kk < 4; ++kk) {
      bf16x8 af[2], bf[2];
      #pragma unroll
      for (int s = 0; s < 2; ++s) {
        int ar = wm + s * 16 + l15;
        af[s] = *(const bf16x8*)(As + ar * 128 + (((kk * 4 + quad) ^ (ar & 15)) << 3));
        int br = wc + s * 16 + l15;
        bf[s] = *(const bf16x8*)(Bs + br * 128 + (((kk * 4 + quad) ^ (br & 15)) << 3));
      }
      #pragma unroll
      for (int sr = 0; sr < 2; ++sr)
        #pragma unroll
        for (int sc = 0; sc < 2; ++sc)
          acc[sr][sc] = __builtin_amdgcn_mfma_f32_16x16x32_bf16(
              af[sr], bf[sc], acc[sr][sc], 0, 0, 0);
    }
  }

  __syncthreads();

  unsigned short* C1u = (unsigned short*)C1v;

  if (mode == MODE_VT) {
    unsigned short* LDb = (unsigned short*)SMEM;   // [64][72], c-major
    #pragma unroll
    for (int sc = 0; sc < 2; ++sc) {
      int cl = wc + sc * 16 + l15;
      float bia = bias[c0 + cl];
      #pragma unroll
      for (int sr = 0; sr < 2; ++sr)
        #pragma unroll
        for (int r = 0; r < 4; ++r) {
          int ml = wm + sr * 16 + quad * 4 + r;
          LDb[cl * 72 + ml] = f2b(acc[sr][sc][r] + bia);
        }
    }
    __syncthreads();
    int row = t >> 2;                 // c-local 0..63
    int c = c0 + row, n = c >> 6, d = c & 63;
    #pragma unroll
    for (int j = 0; j < 2; ++j) {
      int mcol = (t & 3) * 16 + j * 8;
      int4 val = *(const int4*)(LDb + row * 72 + mcol);
      int m = r0 + mcol, bb = m >> 11, l = m & 2047;
      *(int4*)(C1u + ((size_t)(bb * NH + n) * DH + d) * LSEQ + l) = val;
    }
  } else {
    unsigned short* LDb = (unsigned short*)SMEM;   // [64][72], m-major
    const int passes = (mode == MODE_QDUAL) ? 2 : 1;
    for (int p = 0; p < passes; ++p) {
      #pragma unroll
      for (int sc = 0; sc < 2; ++sc) {
        int cl = wc + sc * 16 + l15;
        int c = c0 + cl;
        float bia = bias[c];
        float ex = (mode == MODE_QDUAL) ? ((p == 0) ? cb2[c] : pb2[c]) : 0.f;
        #pragma unroll
        for (int sr = 0; sr < 2; ++sr)
          #pragma unroll
          for (int r = 0; r < 4; ++r) {
            int ml = wm + sr * 16 + quad * 4 + r;
            float v = acc[sr][sc][r] + bia;
            if (mode == MODE_QDUAL) v = (v + ex) * 0.125f;
            if (mode == MODE_GELU)
              v = 0.5f * v * (1.0f + erff(v * 0.70710678118654752f));
            LDb[ml * 72 + cl] = f2b(v);
          }
      }
      __syncthreads();
      int row = t >> 2;               // m-local 0..63
      #pragma unroll
      for (int j = 0; j < 2; ++j) {
        int col = (t & 3) * 16 + j * 8;
        int4 val = *(const int4*)(LDb + row * 72 + col);
        unsigned short* dst;
        int c = c0 + col, n = c >> 6, d = c & 63;
        if (mode == MODE_RE) {
          int m = r0 + row;
          dst = C1u + ((size_t)n * LSEQ + (LSEQ - 1 - m)) * DH + d;
        } else if (mode == MODE_GELU) {
          dst = C1u + (size_t)(r0 + row) * 512 + c0 + col;
        } else if (mode == MODE_B16RES) {
          int m = r0 + row;
          size_t gofs = (size_t)m * 512 + c0 + col;
          unsigned short tmp[8];
          *(int4*)tmp = val;
          if (resf) {
            float4 ra = *(const float4*)(resf + gofs);
            float4 rb = *(const float4*)(resf + gofs + 4);
            tmp[0] = f2b(b2f(tmp[0]) + ra.x); tmp[1] = f2b(b2f(tmp[1]) + ra.y);
            tmp[2] = f2b(b2f(tmp[2]) + ra.z); tmp[3] = f2b(b2f(tmp[3]) + ra.w);
            tmp[4] = f2b(b2f(tmp[4]) + rb.x); tmp[5] = f2b(b2f(tmp[5]) + rb.y);
            tmp[6] = f2b(b2f(tmp[6]) + rb.z); tmp[7] = f2b(b2f(tmp[7]) + rb.w);
          } else {
            ushort4 sa = *(const ushort4*)(res16 + gofs);
            ushort4 sb = *(const ushort4*)(res16 + gofs + 4);
            tmp[0] = f2b(b2f(tmp[0]) + b2f(sa.x)); tmp[1] = f2b(b2f(tmp[1]) + b2f(sa.y));
            tmp[2] = f2b(b2f(tmp[2]) + b2f(sa.z)); tmp[3] = f2b(b2f(tmp[3]) + b2f(sa.w));
            tmp[4] = f2b(b2f(tmp[4]) + b2f(sb.x)); tmp[5] = f2b(b2f(tmp[5]) + b2f(sb.y));
            tmp[6] = f2b(b2f(tmp[6]) + b2f(sb.z)); tmp[7] = f2b(b2f(tmp[7]) + b2f(sb.w));
          }
          val = *(int4*)tmp;
          dst = C1u + gofs;
        } else { // KV
          int m = r0 + row, bb = m >> 11, l = m & 2047;
          dst = C1u + ((size_t)(bb * NH + n) * LSEQ + l) * DH + d;
        }
        *(int4*)dst = val;
      }
      if (p + 1 < passes) __syncthreads();
    }
  }
}

__global__ __launch_bounds__(256, 4) void gemm_mfma(
    const unsigned short* __restrict__ A, const unsigned short* __restrict__ BT,
    const float* __restrict__ bias, const float* __restrict__ resf,
    const unsigned short* __restrict__ res16,
    void* __restrict__ C1v, int mode)
{
  __shared__ __align__(16) char SMEM[32768];
  gemm_core(A, BT, bias, nullptr, nullptr, resf, res16, C1v, nullptr, mode,
            blockIdx.x, blockIdx.y, SMEM);
}

// ---------------------------------------------------------------------------
// R12 merged QKV projection (BK=64, 8-chunk swizzle — unchanged, proven).
// z=1 blocks run the small re GEMM (by<32) via the BK=128 gemm_core.
// ---------------------------------------------------------------------------
__global__ __launch_bounds__(256, 4) void qkv3(
    const unsigned short* __restrict__ xb, const unsigned short* __restrict__ posb,
    const unsigned short* __restrict__ wT,
    const float* __restrict__ bq, const float* __restrict__ bk,
    const float* __restrict__ bv, const float* __restrict__ br,
    const float* __restrict__ cbv, const float* __restrict__ pbv,
    unsigned short* __restrict__ qcb, unsigned short* __restrict__ qpb,
    unsigned short* __restrict__ kbb, unsigned short* __restrict__ vtb,
    unsigned short* __restrict__ rebb)
{
  __shared__ __align__(16) char SMEM[32768];
  if (blockIdx.z == 1) {
    if (blockIdx.y < 32)
      gemm_core(posb, wT + 3 * 262144, br, nullptr, nullptr, nullptr, nullptr,
                rebb, nullptr, MODE_RE, blockIdx.x, blockIdx.y, SMEM);
    return;
  }

  unsigned short* As  = (unsigned short*)SMEM;            // [64][64] 8 KB
  unsigned short* Bqs = (unsigned short*)(SMEM + 8192);
  unsigned short* Bks = (unsigned short*)(SMEM + 16384);
  unsigned short* Bvs = (unsigned short*)(SMEM + 24576);
  const unsigned short* WqT = wT;
  const unsigned short* WkT = wT + 262144;
  const unsigned short* WvT = wT + 2 * 262144;

  const int t = threadIdx.x;
  const int w = t >> 6, lane = t & 63;
  const int l15 = lane & 15, quad = lane >> 4;
  const int r0 = blockIdx.y * 64;
  const int c0 = blockIdx.x * 64;
  const int wm = (w >> 1) * 32, wc = (w & 1) * 32;

  f32x4 accq[2][2], acck[2][2], accv[2][2];
  #pragma unroll
  for (int sr = 0; sr < 2; ++sr)
    #pragma unroll
    for (int sc = 0; sc < 2; ++sc) {
      accq[sr][sc] = (f32x4){0.f, 0.f, 0.f, 0.f};
      acck[sr][sc] = (f32x4){0.f, 0.f, 0.f, 0.f};
      accv[sr][sc] = (f32x4){0.f, 0.f, 0.f, 0.f};
    }

  const int sub = lane >> 3;
  const int g   = (lane & 7) ^ sub;

  for (int k0 = 0; k0 < 512; k0 += 64) {
    __syncthreads();
    #pragma unroll
    for (int i = 0; i < 2; ++i) {
      int rowb = w * 16 + i * 8;
      size_t asrc = (size_t)(r0 + rowb + sub) * 512 + k0 + g * 8;
      size_t bsrc = (size_t)(c0 + rowb + sub) * 512 + k0 + g * 8;
      gl_lds16(xb  + asrc, As  + rowb * 64);
      gl_lds16(WqT + bsrc, Bqs + rowb * 64);
      gl_lds16(WkT + bsrc, Bks + rowb * 64);
      gl_lds16(WvT + bsrc, Bvs + rowb * 64);
    }
    __syncthreads();

    #pragma unroll
    for (int kk = 0; kk < 2; ++kk) {
      bf16x8 af[2];
      #pragma unroll
      for (int s = 0; s < 2; ++s) {
        int ar = wm + s * 16 + l15;
        af[s] = *(const bf16x8*)(As + ar * 64 + (((quad + 4 * kk) ^ (ar & 7)) << 3));
      }
      #pragma unroll
      for (int s = 0; s < 2; ++s) {
        int br_ = wc + s * 16 + l15;
        int off = br_ * 64 + (((quad + 4 * kk) ^ (br_ & 7)) << 3);
        bf16x8 bq8 = *(const bf16x8*)(Bqs + off);
        bf16x8 bk8 = *(const bf16x8*)(Bks + off);
        bf16x8 bv8 = *(const bf16x8*)(Bvs + off);
        #pragma unroll
        for (int sr = 0; sr < 2; ++sr) {
          accq[sr][s] = __builtin_amdgcn_mfma_f32_16x16x32_bf16(af[sr], bq8, accq[sr][s], 0, 0, 0);
          acck[sr][s] = __builtin_amdgcn_mfma_f32_16x16x32_bf16(af[sr], bk8, acck[sr][s], 0, 0, 0);
          accv[sr][s] = __builtin_amdgcn_mfma_f32_16x16x32_bf16(af[sr], bv8, accv[sr][s], 0, 0, 0);
        }
      }
    }
  }

  // ---- epilogues: Q (2 passes), K, V — sequential, reusing SMEM ----
  unsigned short* LDb = (unsigned short*)SMEM;   // [64][72]

  // Q dual passes
  #pragma unroll
  for (int p = 0; p < 2; ++p) {
    __syncthreads();
    #pragma unroll
    for (int sc = 0; sc < 2; ++sc) {
      int cl = wc + sc * 16 + l15;
      int c = c0 + cl;
      float bia = bq[c] + ((p == 0) ? cbv[c] : pbv[c]);
      #pragma unroll
      for (int sr = 0; sr < 2; ++sr)
        #pragma unroll
        for (int r = 0; r < 4; ++r) {
          int ml = wm + sr * 16 + quad * 4 + r;
          LDb[ml * 72 + cl] = f2b((accq[sr][sc][r] + bia) * 0.125f);
        }
    }
    __syncthreads();
    int row = t >> 2;
    unsigned short* C = (p == 0) ? qcb : qpb;
    #pragma unroll
    for (int j = 0; j < 2; ++j) {
      int col = (t & 3) * 16 + j * 8;
      int4 val = *(const int4*)(LDb + row * 72 + col);
      int c = c0 + col, n = c >> 6, d = c & 63;
      int m = r0 + row, bb = m >> 11, l = m & 2047;
      *(int4*)(C + ((size_t)(bb * NH + n) * LSEQ + l) * DH + d) = val;
    }
  }

  // K pass
  __syncthreads();
  #pragma unroll
  for (int sc = 0; sc < 2; ++sc) {
    int cl = wc + sc * 16 + l15;
    float bia = bk[c0 + cl];
    #pragma unroll
    for (int sr = 0; sr < 2; ++sr)
      #pragma unroll
      for (int r = 0; r < 4; ++r) {
        int ml = wm + sr * 16 + quad * 4 + r;
        LDb[ml * 72 + cl] = f2b(acck[sr][sc][r] + bia);
      }
  }
  __syncthreads();
  {
    int row = t >> 2;
    #pragma unroll
    for (int j = 0; j < 2; ++j) {
      int col = (t & 3) * 16 + j * 8;
      int4 val = *(const int4*)(LDb + row * 72 + col);
      int c = c0 + col, n = c >> 6, d = c & 63;
      int m = r0 + row, bb = m >> 11, l = m & 2047;
      *(int4*)(kbb + ((size_t)(bb * NH + n) * LSEQ + l) * DH + d) = val;
    }
  }

  // V pass (c-major for transposed store)
  __syncthreads();
  #pragma unroll
  for (int sc = 0; sc < 2; ++sc) {
    int cl = wc + sc * 16 + l15;
    float bia = bv[c0 + cl];
    #pragma unroll
    for (int sr = 0; sr < 2; ++sr)
      #pragma unroll
      for (int r = 0; r < 4; ++r) {
        int ml = wm + sr * 16 + quad * 4 + r;
        LDb[cl * 72 + ml] = f2b(accv[sr][sc][r] + bia);
      }
  }
  __syncthreads();
  {
    int row = t >> 2;                 // c-local
    int c = c0 + row, n = c >> 6, d = c & 63;
    #pragma unroll
    for (int j = 0; j < 2; ++j) {
      int mcol = (t & 3) * 16 + j * 8;
      int4 val = *(const int4*)(LDb + row * 72 + mcol);
      int m = r0 + mcol, bb = m >> 11, l = m & 2047;
      *(int4*)(vtb + ((size_t)(bb * NH + n) * DH + d) * LSEQ + l) = val;
    }
  }
}

// ---------------------------------------------------------------------------
// MFMA flash attention (R7-proven exact).
// ---------------------------------------------------------------------------
#define PROW(i) ((i) * 72 + (((i) >> 2) << 3))

__global__ __launch_bounds__(256, 3) void attn_mfma(
    const unsigned short* __restrict__ qcb, const unsigned short* __restrict__ qpb,
    const unsigned short* __restrict__ kbb, const unsigned short* __restrict__ vtb,
    const unsigned short* __restrict__ rebb, unsigned short* __restrict__ outb)
{
  __shared__ __align__(16) unsigned short Ks[64 * 72];
  __shared__ __align__(16) unsigned short Vts[64 * 72];
  __shared__ __align__(16) unsigned short Res[128 * 72];
  __shared__ __align__(16) unsigned short TPb[4 * 16 * 84];

  const int t = threadIdx.x;
  const int bn = blockIdx.x;
  const int b = bn >> 3, n = bn & 7;
  const int ib = 31 - blockIdx.y;
  const int i0 = ib * 64;
  const int w = t >> 6;
  const int lane = t & 63;
  const int l15 = lane & 15, quad = lane >> 4;

  bf16x8 qcf[2], qpf[2];
  {
    size_t base = ((size_t)bn * LSEQ + i0 + 16 * w + l15) * DH + quad * 8;
    qcf[0] = *(const bf16x8*)(qcb + base);
    qcf[1] = *(const bf16x8*)(qcb + base + 32);
    qpf[0] = *(const bf16x8*)(qpb + base);
    qpf[1] = *(const bf16x8*)(qpb + base + 32);
  }

  f32x4 Of[4];
  #pragma unroll
  for (int s = 0; s < 4; ++s) Of[s] = (f32x4){0.f, 0.f, 0.f, 0.f};
  float lsum[4] = {0.f, 0.f, 0.f, 0.f};

  unsigned short* Tw = TPb + w * 1344;
  const int Ibase = i0 + 16 * w;
  const int nt = ib + 1;

  const int r2 = t >> 2, gl2 = t & 3;
  const int r1 = t >> 1, h1 = t & 1;

  for (int tt = 0; tt < nt; ++tt) {
    const int j0 = tt * 64;
    const int db = i0 - j0;

    const int4* skp = (const int4*)(kbb + ((size_t)bn * LSEQ + j0 + r2) * DH + gl2 * 16);
    int4 ka0 = skp[0], ka1 = skp[1];
    const int4* svp = (const int4*)(vtb + ((size_t)bn * DH + r2) * LSEQ + j0 + gl2 * 16);
    int4 va0 = svp[0], va1 = svp[1];
    int dist = db - 63 + r1;
    int4 ra[2][2];
    #pragma unroll
    for (int gi = 0; gi < 2; ++gi) {
      if (dist >= 0 && dist < LSEQ) {
        const int4* srp = (const int4*)(rebb + ((size_t)n * LSEQ + dist) * DH + (h1 * 2 + gi) * 16);
        ra[gi][0] = srp[0]; ra[gi][1] = srp[1];
      } else {
        int4 z = {0, 0, 0, 0};
        ra[gi][0] = z; ra[gi][1] = z;
      }
    }
    __syncthreads();
    {
      unsigned short* dk = Ks + r2 * 72 + ((gl2 ^ (r2 & 3)) * 16);
      *(int4*)(dk) = ka0; *(int4*)(dk + 8) = ka1;
      unsigned short* dv = Vts + r2 * 72 + ((gl2 ^ (r2 & 3)) * 16);
      *(int4*)(dv) = va0; *(int4*)(dv + 8) = va1;
      #pragma unroll
      for (int gi = 0; gi < 2; ++gi) {
        int gl = h1 * 2 + gi;
        unsigned short* dr = Res + r1 * 72 + ((gl ^ (r1 & 3)) * 16);
        *(int4*)(dr) = ra[gi][0]; *(int4*)(dr + 8) = ra[gi][1];
      }
    }
    __syncthreads();

    f32x4 Sf[4];
    #pragma unroll
    for (int s = 0; s < 4; ++s) {
      f32x4 acc = {0.f, 0.f, 0.f, 0.f};
      int row = 16 * s + l15;
      #pragma unroll
      for (int kk = 0; kk < 2; ++kk) {
        int g = (quad >> 1) + 2 * kk;
        bf16x8 bfr = *(const bf16x8*)(Ks + row * 72 + ((g ^ (row & 3)) * 16) + (quad & 1) * 8);
        acc = __builtin_amdgcn_mfma_f32_16x16x32_bf16(qcf[kk], bfr, acc, 0, 0, 0);
      }
      Sf[s] = acc;
    }
    #pragma unroll
    for (int s = 0; s < 5; ++s) {
      f32x4 acc = {0.f, 0.f, 0.f, 0.f};
      int row = 16 * w + 16 * s + l15;
      #pragma unroll
      for (int kk = 0; kk < 2; ++kk) {
        int g = (quad >> 1) + 2 * kk;
        bf16x8 bfr = *(const bf16x8*)(Res + row * 72 + ((g ^ (row & 3)) * 16) + (quad & 1) * 8);
        acc = __builtin_amdgcn_mfma_f32_16x16x32_bf16(qpf[kk], bfr, acc, 0, 0, 0);
      }
      #pragma unroll
      for (int r = 0; r < 4; ++r) {
        int i = quad * 4 + r;
        Tw[i * 84 + 16 * s + l15] = f2b(acc[r]);
      }
    }
    asm volatile("s_waitcnt lgkmcnt(0)" ::: "memory");

    float p_s[4][4];
    #pragma unroll
    for (int s = 0; s < 4; ++s)
      #pragma unroll
      for (int r = 0; r < 4; ++r) {
        int i = quad * 4 + r;
        float tval = b2f(Tw[i * 84 + 63 + i - 16 * s - l15]);
        float v = Sf[s][r] + tval;
        int j = j0 + 16 * s + l15;
        float p = (j <= Ibase + i) ? __expf(v) : 0.0f;
        p_s[s][r] = p;
        lsum[r] += p;
      }
    #pragma unroll
    for (int s = 0; s < 4; ++s)
      #pragma unroll
      for (int r = 0; r < 4; ++r) {
        int i = quad * 4 + r;
        Tw[PROW(i) + ((s ^ (i & 3)) * 16) + l15] = f2b(p_s[s][r]);
      }
    asm volatile("s_waitcnt lgkmcnt(0)" ::: "memory");

    #pragma unroll
    for (int kk = 0; kk < 2; ++kk) {
      int g = (quad >> 1) + 2 * kk;
      bf16x8 pa = *(const bf16x8*)(Tw + PROW(l15) + ((g ^ (l15 & 3)) * 16) + (quad & 1) * 8);
      #pragma unroll
      for (int s = 0; s < 4; ++s) {
        int d = 16 * s + l15;
        bf16x8 vb8 = *(const bf16x8*)(Vts + d * 72 + ((g ^ (d & 3)) * 16) + (quad & 1) * 8);
        Of[s] = __builtin_amdgcn_mfma_f32_16x16x32_bf16(pa, vb8, Of[s], 0, 0, 0);
      }
    }
  }

  #pragma unroll
  for (int r = 0; r < 4; ++r) {
    float rs = lsum[r];
    rs += __shfl_xor(rs, 1, 64);
    rs += __shfl_xor(rs, 2, 64);
    rs += __shfl_xor(rs, 4, 64);
    rs += __shfl_xor(rs, 8, 64);
    float linv = 1.0f / rs;
    int I = Ibase + quad * 4 + r;
    size_t base = ((size_t)b * LSEQ + I) * HDIM + n * DH;
    #pragma unroll
    for (int s = 0; s < 4; ++s)
      outb[base + 16 * s + l15] = f2b(Of[s][r] * linv);
  }
}

// ---------------------------------------------------------------------------
// LayerNorm, bf16 input, one wave per row (4 rows/block), shuffle-only.
// ---------------------------------------------------------------------------
__global__ __launch_bounds__(256) void ln_b16(
    const unsigned short* __restrict__ xin, const float* __restrict__ w,
    const float* __restrict__ bb, float* __restrict__ outf,
    unsigned short* __restrict__ out16)
{
  const int t = threadIdx.x;
  const int lane = t & 63;
  const int row = blockIdx.x * 4 + (t >> 6);
  const size_t base = (size_t)row * 512 + lane * 8;

  unsigned short v16[8];
  *(int4*)v16 = *(const int4*)(xin + base);
  float v[8];
  float s = 0.f;
  #pragma unroll
  for (int i = 0; i < 8; ++i) { v[i] = b2f(v16[i]); s += v[i]; }
  #pragma unroll
  for (int off = 32; off >= 1; off >>= 1) s += __shfl_xor(s, off, 64);
  float mean = s * (1.0f / 512.0f);
  float s2 = 0.f;
  #pragma unroll
  for (int i = 0; i < 8; ++i) { float d = v[i] - mean; s2 += d * d; }
  #pragma unroll
  for (int off = 32; off >= 1; off >>= 1) s2 += __shfl_xor(s2, off, 64);
  float inv = 1.0f / sqrtf(s2 * (1.0f / 512.0f) + 1e-12f);

  float4 wa = *(const float4*)(w + lane * 8);
  float4 wb = *(const float4*)(w + lane * 8 + 4);
  float4 ba = *(const float4*)(bb + lane * 8);
  float4 bbv = *(const float4*)(bb + lane * 8 + 4);
  float o[8];
  o[0] = wa.x * (v[0] - mean) * inv + ba.x;
  o[1] = wa.y * (v[1] - mean) * inv + ba.y;
  o[2] = wa.z * (v[2] - mean) * inv + ba.z;
  o[3] = wa.w * (v[3] - mean) * inv + ba.w;
  o[4] = wb.x * (v[4] - mean) * inv + bbv.x;
  o[5] = wb.y * (v[5] - mean) * inv + bbv.y;
  o[6] = wb.z * (v[6] - mean) * inv + bbv.z;
  o[7] = wb.w * (v[7] - mean) * inv + bbv.w;
  if (outf) {
    float4 f0 = {o[0], o[1], o[2], o[3]}, f1 = {o[4], o[5], o[6], o[7]};
    *(float4*)(outf + base) = f0;
    *(float4*)(outf + base + 4) = f1;
  }
  if (out16) {
    unsigned short u[8];
    #pragma unroll
    for (int i = 0; i < 8; ++i) u[i] = f2b(o[i]);
    *(int4*)(out16 + base) = *(int4*)u;
  }
}

// ---------------------------------------------------------------------------
extern "C" void kernel_launch(void* const* d_in, const int* in_sizes, int n_in,
                              void* d_out, int out_size, void* d_ws, size_t ws_size,
                              hipStream_t stream)
{
  (void)in_sizes; (void)n_in; (void)out_size; (void)ws_size;
  const float* x   = (const float*)d_in[0];
  const float* pos = (const float*)d_in[1];
  const float* Wq  = (const float*)d_in[2];
  const float* bq  = (const float*)d_in[3];
  const float* Wk  = (const float*)d_in[4];
  const float* bk  = (const float*)d_in[5];
  const float* Wv  = (const float*)d_in[6];
  const float* bv  = (const float*)d_in[7];
  const float* Wr  = (const float*)d_in[8];
  const float* br  = (const float*)d_in[9];
  const float* cbv = (const float*)d_in[10];
  const float* pbv = (const float*)d_in[11];
  const float* Wc  = (const float*)d_in[12];
  const float* bc  = (const float*)d_in[13];
  const float* W1  = (const float*)d_in[14];
  const float* b1  = (const float*)d_in[15];
  const float* W2  = (const float*)d_in[16];
  const float* b2  = (const float*)d_in[17];
  const float* lnw = (const float*)d_in[18];
  const float* lnb = (const float*)d_in[19];
  char* ws = (char*)d_ws;
  float* outp = (float*)d_out;

  unsigned short* xb   = (unsigned short*)(ws);
  unsigned short* posb = (unsigned short*)(ws + 8388608);
  unsigned short* wT   = (unsigned short*)(ws + 10485760);
  unsigned short* qcb  = (unsigned short*)(ws + 14155776);
  unsigned short* qpb  = (unsigned short*)(ws + 22544384);
  unsigned short* kbb  = (unsigned short*)(ws + 30932992);
  unsigned short* vtb  = (unsigned short*)(ws + 39321600);
  unsigned short* rebb = (unsigned short*)(ws + 47710208);
  unsigned short* WcT = wT + 4 * 262144;
  unsigned short* W1T = wT + 5 * 262144;
  unsigned short* W2T = wT + 6 * 262144;
  unsigned short* attnb  = (unsigned short*)d_out;
  unsigned short* cpre16 = (unsigned short*)(ws + 14155776);  // over qcb
  unsigned short* ab16   = (unsigned short*)(ws);             // over xb
  unsigned short* h1b    = (unsigned short*)(ws + 30932992);  // over kbb
  unsigned short* h2b16  = (unsigned short*)(ws + 22544384);  // over qpb

  dim3 blk(256);
  dim3 g8(8, 128);   // M=8192: 64x64 tiles -> 1024 blocks (4/CU)

  conv_all<<<dim3(4096, 1, 3), blk, 0, stream>>>(
      x, pos, Wq, Wk, Wv, Wr, Wc, W1, W2, xb, posb, wT);

  // merged Q/K/V (z=0) + re (z=1)
  qkv3<<<dim3(8, 128, 2), blk, 0, stream>>>(
      xb, posb, wT, bq, bk, bv, br, cbv, pbv, qcb, qpb, kbb, vtb, rebb);

  attn_mfma<<<dim3(32, 32), blk, 0, stream>>>(qcb, qpb, kbb, vtb, rebb, attnb);

  gemm_mfma<<<g8, blk, 0, stream>>>(attnb, WcT, bc, x, nullptr, cpre16, MODE_B16RES);
  ln_b16<<<2048, blk, 0, stream>>>(cpre16, lnw, lnb, nullptr, ab16);
  gemm_mfma<<<g8, blk, 0, stream>>>(ab16, W1T, b1, nullptr, nullptr, h1b, MODE_GELU);
  gemm_mfma<<<g8, blk, 0, stream>>>(h1b, W2T, b2, nullptr, ab16, h2b16, MODE_B16RES);
  ln_b16<<<2048, blk, 0, stream>>>(h2b16, lnw, lnb, outp, nullptr);
}

// Round 14
// 286.869 us; speedup vs baseline: 1.0421x; 1.0421x over previous
//
#include <hip/hip_runtime.h>
#include <math.h>

#define HDIM 512
#define LSEQ 2048
#define NH 8
#define DH 64
#define NEGBIG (-3.0e38f)

#define MODE_QDUAL  0
#define MODE_KV     1
#define MODE_VT     2
#define MODE_RE     3
#define MODE_B16RES 4
#define MODE_GELU   5

typedef short bf16x8 __attribute__((ext_vector_type(8)));
typedef float f32x4 __attribute__((ext_vector_type(4)));

__device__ __forceinline__ unsigned short f2b(float f) {
  union { float f; unsigned u; } x; x.f = f;
  unsigned r = x.u + 0x7FFF + ((x.u >> 16) & 1);
  return (unsigned short)(r >> 16);
}
__device__ __forceinline__ float b2f(unsigned short u) {
  union { unsigned u; float f; } x; x.u = ((unsigned)u) << 16;
  return x.f;
}

// async global->LDS, 16B per lane; LDS dest = wave-uniform base + lane*16
__device__ __forceinline__ void gl_lds16(const void* g, void* l) {
  __builtin_amdgcn_global_load_lds(
      (const __attribute__((address_space(1))) void*)g,
      (__attribute__((address_space(3))) void*)l, 16, 0, 0);
}

// ---------------------------------------------------------------------------
// Fused prep: z=0 convert x, z=1 convert pos_enc, z=2 convert/transpose weights
// ---------------------------------------------------------------------------
__global__ __launch_bounds__(256) void conv_all(
    const float* __restrict__ x, const float* __restrict__ pos,
    const float* __restrict__ Wq, const float* __restrict__ Wk,
    const float* __restrict__ Wv, const float* __restrict__ Wr,
    const float* __restrict__ Wc, const float* __restrict__ W1,
    const float* __restrict__ W2,
    unsigned short* __restrict__ xb, unsigned short* __restrict__ posb,
    unsigned short* __restrict__ wT)
{
  const int t = threadIdx.x;
  const int z = blockIdx.z;
  if (z == 0) {
    int idx = blockIdx.x * 256 + t;
    float4 v = ((const float4*)x)[idx];
    ushort4 o; o.x = f2b(v.x); o.y = f2b(v.y); o.z = f2b(v.z); o.w = f2b(v.w);
    ((ushort4*)xb)[idx] = o;
  } else if (z == 1) {
    int idx = blockIdx.x * 256 + t;
    if (idx < 262144) {
      float4 v = ((const float4*)pos)[idx];
      ushort4 o; o.x = f2b(v.x); o.y = f2b(v.y); o.z = f2b(v.z); o.w = f2b(v.w);
      ((ushort4*)posb)[idx] = o;
    }
  } else {
    if (blockIdx.x >= 448) return;
    const int widx = blockIdx.x >> 6;
    const int tile = blockIdx.x & 63;
    const float* src = (widx == 0) ? Wq : (widx == 1) ? Wk : (widx == 2) ? Wv :
                       (widx == 3) ? Wr : (widx == 4) ? Wc : (widx == 5) ? W1 : W2;
    unsigned short* dst = wT + (size_t)widx * 262144;
    if (widx < 4) {
      __shared__ float td[64][65];
      const int h0 = (tile >> 3) * 64;
      const int n  = tile & 7;
      #pragma unroll
      for (int it = 0; it < 4; ++it) {
        int row = it * 16 + (t >> 4), dc = (t & 15) * 4;
        float4 v = *(const float4*)(src + (size_t)n * 32768 + (size_t)(h0 + row) * 64 + dc);
        td[row][dc] = v.x; td[row][dc + 1] = v.y; td[row][dc + 2] = v.z; td[row][dc + 3] = v.w;
      }
      __syncthreads();
      #pragma unroll
      for (int it = 0; it < 4; ++it) {
        int d = it * 16 + (t >> 4), h4 = (t & 15) * 4;
        ushort4 o;
        o.x = f2b(td[h4 + 0][d]); o.y = f2b(td[h4 + 1][d]);
        o.z = f2b(td[h4 + 2][d]); o.w = f2b(td[h4 + 3][d]);
        *(ushort4*)(dst + (size_t)(n * 64 + d) * 512 + h0 + h4) = o;
      }
    } else {
      #pragma unroll
      for (int i = 0; i < 4; ++i) {
        int f4 = tile * 1024 + i * 256 + t;
        float4 v = ((const float4*)src)[f4];
        ushort4 o; o.x = f2b(v.x); o.y = f2b(v.y); o.z = f2b(v.z); o.w = f2b(v.w);
        ((ushort4*)dst)[f4] = o;
      }
    }
  }
}

// ---------------------------------------------------------------------------
// MFMA GEMM core, 64x64 tile, BK=64 (R12-proven best). 4 waves, each 32x32.
// ---------------------------------------------------------------------------
__device__ __forceinline__ void gemm_core(
    const unsigned short* __restrict__ A, const unsigned short* __restrict__ BT,
    const float* __restrict__ bias, const float* __restrict__ cb2,
    const float* __restrict__ pb2, const float* __restrict__ resf,
    const unsigned short* __restrict__ res16,
    void* __restrict__ C1v, unsigned short* __restrict__ C2, int mode,
    int bx, int by, char* SMEM)
{
  unsigned short* As = (unsigned short*)SMEM;            // [64][64] 8 KB
  unsigned short* Bs = (unsigned short*)(SMEM + 8192);   // [64][64] 8 KB

  const int t = threadIdx.x;
  const int w = t >> 6, lane = t & 63;
  const int l15 = lane & 15, quad = lane >> 4;
  const int r0 = by * 64;
  const int c0 = bx * 64;
  const int wm = (w >> 1) * 32, wc = (w & 1) * 32;

  f32x4 acc[2][2];
  #pragma unroll
  for (int sr = 0; sr < 2; ++sr)
    #pragma unroll
    for (int sc = 0; sc < 2; ++sc) acc[sr][sc] = (f32x4){0.f, 0.f, 0.f, 0.f};

  const int sub = lane >> 3;
  const int g   = (lane & 7) ^ sub;

  for (int k0 = 0; k0 < 512; k0 += 64) {
    __syncthreads();
    #pragma unroll
    for (int i = 0; i < 2; ++i) {
      int rowb = w * 16 + i * 8;
      gl_lds16(A  + (size_t)(r0 + rowb + sub) * 512 + k0 + g * 8, As + rowb * 64);
      gl_lds16(BT + (size_t)(c0 + rowb + sub) * 512 + k0 + g * 8, Bs + rowb * 64);
    }
    __syncthreads();

    #pragma unroll
    for (int kk = 0; kk < 2; ++kk) {
      bf16x8 af[2], bf[2];
      #pragma unroll
      for (int s = 0; s < 2; ++s) {
        int ar = wm + s * 16 + l15;
        af[s] = *(const bf16x8*)(As + ar * 64 + (((quad + 4 * kk) ^ (ar & 7)) << 3));
        int br = wc + s * 16 + l15;
        bf[s] = *(const bf16x8*)(Bs + br * 64 + (((quad + 4 * kk) ^ (br & 7)) << 3));
      }
      #pragma unroll
      for (int sr = 0; sr < 2; ++sr)
        #pragma unroll
        for (int sc = 0; sc < 2; ++sc)
          acc[sr][sc] = __builtin_amdgcn_mfma_f32_16x16x32_bf16(
              af[sr], bf[sc], acc[sr][sc], 0, 0, 0);
    }
  }

  __syncthreads();

  unsigned short* C1u = (unsigned short*)C1v;

  if (mode == MODE_VT) {
    unsigned short* LDb = (unsigned short*)SMEM;   // [64][72], c-major
    #pragma unroll
    for (int sc = 0; sc < 2; ++sc) {
      int cl = wc + sc * 16 + l15;
      float bia = bias[c0 + cl];
      #pragma unroll
      for (int sr = 0; sr < 2; ++sr)
        #pragma unroll
        for (int r = 0; r < 4; ++r) {
          int ml = wm + sr * 16 + quad * 4 + r;
          LDb[cl * 72 + ml] = f2b(acc[sr][sc][r] + bia);
        }
    }
    __syncthreads();
    int row = t >> 2;                 // c-local 0..63
    int c = c0 + row, n = c >> 6, d = c & 63;
    #pragma unroll
    for (int j = 0; j < 2; ++j) {
      int mcol = (t & 3) * 16 + j * 8;
      int4 val = *(const int4*)(LDb + row * 72 + mcol);
      int m = r0 + mcol, bb = m >> 11, l = m & 2047;
      *(int4*)(C1u + ((size_t)(bb * NH + n) * DH + d) * LSEQ + l) = val;
    }
  } else {
    unsigned short* LDb = (unsigned short*)SMEM;   // [64][72], m-major
    const int passes = (mode == MODE_QDUAL) ? 2 : 1;
    for (int p = 0; p < passes; ++p) {
      #pragma unroll
      for (int sc = 0; sc < 2; ++sc) {
        int cl = wc + sc * 16 + l15;
        int c = c0 + cl;
        float bia = bias[c];
        float ex = (mode == MODE_QDUAL) ? ((p == 0) ? cb2[c] : pb2[c]) : 0.f;
        #pragma unroll
        for (int sr = 0; sr < 2; ++sr)
          #pragma unroll
          for (int r = 0; r < 4; ++r) {
            int ml = wm + sr * 16 + quad * 4 + r;
            float v = acc[sr][sc][r] + bia;
            if (mode == MODE_QDUAL) v = (v + ex) * 0.125f;
            if (mode == MODE_GELU)
              v = 0.5f * v * (1.0f + erff(v * 0.70710678118654752f));
            LDb[ml * 72 + cl] = f2b(v);
          }
      }
      __syncthreads();
      int row = t >> 2;               // m-local 0..63
      #pragma unroll
      for (int j = 0; j < 2; ++j) {
        int col = (t & 3) * 16 + j * 8;
        int4 val = *(const int4*)(LDb + row * 72 + col);
        unsigned short* dst;
        int c = c0 + col, n = c >> 6, d = c & 63;
        if (mode == MODE_RE) {
          int m = r0 + row;
          dst = C1u + ((size_t)n * LSEQ + (LSEQ - 1 - m)) * DH + d;
        } else if (mode == MODE_GELU) {
          dst = C1u + (size_t)(r0 + row) * 512 + c0 + col;
        } else if (mode == MODE_B16RES) {
          int m = r0 + row;
          size_t gofs = (size_t)m * 512 + c0 + col;
          unsigned short tmp[8];
          *(int4*)tmp = val;
          if (resf) {
            float4 ra = *(const float4*)(resf + gofs);
            float4 rb = *(const float4*)(resf + gofs + 4);
            tmp[0] = f2b(b2f(tmp[0]) + ra.x); tmp[1] = f2b(b2f(tmp[1]) + ra.y);
            tmp[2] = f2b(b2f(tmp[2]) + ra.z); tmp[3] = f2b(b2f(tmp[3]) + ra.w);
            tmp[4] = f2b(b2f(tmp[4]) + rb.x); tmp[5] = f2b(b2f(tmp[5]) + rb.y);
            tmp[6] = f2b(b2f(tmp[6]) + rb.z); tmp[7] = f2b(b2f(tmp[7]) + rb.w);
          } else {
            ushort4 sa = *(const ushort4*)(res16 + gofs);
            ushort4 sb = *(const ushort4*)(res16 + gofs + 4);
            tmp[0] = f2b(b2f(tmp[0]) + b2f(sa.x)); tmp[1] = f2b(b2f(tmp[1]) + b2f(sa.y));
            tmp[2] = f2b(b2f(tmp[2]) + b2f(sa.z)); tmp[3] = f2b(b2f(tmp[3]) + b2f(sa.w));
            tmp[4] = f2b(b2f(tmp[4]) + b2f(sb.x)); tmp[5] = f2b(b2f(tmp[5]) + b2f(sb.y));
            tmp[6] = f2b(b2f(tmp[6]) + b2f(sb.z)); tmp[7] = f2b(b2f(tmp[7]) + b2f(sb.w));
          }
          val = *(int4*)tmp;
          dst = C1u + gofs;
        } else { // KV
          int m = r0 + row, bb = m >> 11, l = m & 2047;
          dst = C1u + ((size_t)(bb * NH + n) * LSEQ + l) * DH + d;
        }
        *(int4*)dst = val;
      }
      if (p + 1 < passes) __syncthreads();
    }
  }
}

__global__ __launch_bounds__(256, 4) void gemm_mfma(
    const unsigned short* __restrict__ A, const unsigned short* __restrict__ BT,
    const float* __restrict__ bias, const float* __restrict__ resf,
    const unsigned short* __restrict__ res16,
    void* __restrict__ C1v, int mode)
{
  __shared__ __align__(16) char SMEM[16384];
  gemm_core(A, BT, bias, nullptr, nullptr, resf, res16, C1v, nullptr, mode,
            blockIdx.x, blockIdx.y, SMEM);
}

// ---------------------------------------------------------------------------
// R12 merged QKV projection (BK=64, proven). z=1 blocks run the re GEMM.
// ---------------------------------------------------------------------------
__global__ __launch_bounds__(256, 4) void qkv3(
    const unsigned short* __restrict__ xb, const unsigned short* __restrict__ posb,
    const unsigned short* __restrict__ wT,
    const float* __restrict__ bq, const float* __restrict__ bk,
    const float* __restrict__ bv, const float* __restrict__ br,
    const float* __restrict__ cbv, const float* __restrict__ pbv,
    unsigned short* __restrict__ qcb, unsigned short* __restrict__ qpb,
    unsigned short* __restrict__ kbb, unsigned short* __restrict__ vtb,
    unsigned short* __restrict__ rebb)
{
  __shared__ __align__(16) char SMEM[32768];
  if (blockIdx.z == 1) {
    if (blockIdx.y < 32)
      gemm_core(posb, wT + 3 * 262144, br, nullptr, nullptr, nullptr, nullptr,
                rebb, nullptr, MODE_RE, blockIdx.x, blockIdx.y, SMEM);
    return;
  }

  unsigned short* As  = (unsigned short*)SMEM;            // [64][64] 8 KB
  unsigned short* Bqs = (unsigned short*)(SMEM + 8192);
  unsigned short* Bks = (unsigned short*)(SMEM + 16384);
  unsigned short* Bvs = (unsigned short*)(SMEM + 24576);
  const unsigned short* WqT = wT;
  const unsigned short* WkT = wT + 262144;
  const unsigned short* WvT = wT + 2 * 262144;

  const int t = threadIdx.x;
  const int w = t >> 6, lane = t & 63;
  const int l15 = lane & 15, quad = lane >> 4;
  const int r0 = blockIdx.y * 64;
  const int c0 = blockIdx.x * 64;
  const int wm = (w >> 1) * 32, wc = (w & 1) * 32;

  f32x4 accq[2][2], acck[2][2], accv[2][2];
  #pragma unroll
  for (int sr = 0; sr < 2; ++sr)
    #pragma unroll
    for (int sc = 0; sc < 2; ++sc) {
      accq[sr][sc] = (f32x4){0.f, 0.f, 0.f, 0.f};
      acck[sr][sc] = (f32x4){0.f, 0.f, 0.f, 0.f};
      accv[sr][sc] = (f32x4){0.f, 0.f, 0.f, 0.f};
    }

  const int sub = lane >> 3;
  const int g   = (lane & 7) ^ sub;

  for (int k0 = 0; k0 < 512; k0 += 64) {
    __syncthreads();
    #pragma unroll
    for (int i = 0; i < 2; ++i) {
      int rowb = w * 16 + i * 8;
      size_t asrc = (size_t)(r0 + rowb + sub) * 512 + k0 + g * 8;
      size_t bsrc = (size_t)(c0 + rowb + sub) * 512 + k0 + g * 8;
      gl_lds16(xb  + asrc, As  + rowb * 64);
      gl_lds16(WqT + bsrc, Bqs + rowb * 64);
      gl_lds16(WkT + bsrc, Bks + rowb * 64);
      gl_lds16(WvT + bsrc, Bvs + rowb * 64);
    }
    __syncthreads();

    #pragma unroll
    for (int kk = 0; kk < 2; ++kk) {
      bf16x8 af[2];
      #pragma unroll
      for (int s = 0; s < 2; ++s) {
        int ar = wm + s * 16 + l15;
        af[s] = *(const bf16x8*)(As + ar * 64 + (((quad + 4 * kk) ^ (ar & 7)) << 3));
      }
      #pragma unroll
      for (int s = 0; s < 2; ++s) {
        int br_ = wc + s * 16 + l15;
        int off = br_ * 64 + (((quad + 4 * kk) ^ (br_ & 7)) << 3);
        bf16x8 bq8 = *(const bf16x8*)(Bqs + off);
        bf16x8 bk8 = *(const bf16x8*)(Bks + off);
        bf16x8 bv8 = *(const bf16x8*)(Bvs + off);
        #pragma unroll
        for (int sr = 0; sr < 2; ++sr) {
          accq[sr][s] = __builtin_amdgcn_mfma_f32_16x16x32_bf16(af[sr], bq8, accq[sr][s], 0, 0, 0);
          acck[sr][s] = __builtin_amdgcn_mfma_f32_16x16x32_bf16(af[sr], bk8, acck[sr][s], 0, 0, 0);
          accv[sr][s] = __builtin_amdgcn_mfma_f32_16x16x32_bf16(af[sr], bv8, accv[sr][s], 0, 0, 0);
        }
      }
    }
  }

  // ---- epilogues: Q (2 passes), K, V — sequential, reusing SMEM ----
  unsigned short* LDb = (unsigned short*)SMEM;   // [64][72]

  #pragma unroll
  for (int p = 0; p < 2; ++p) {
    __syncthreads();
    #pragma unroll
    for (int sc = 0; sc < 2; ++sc) {
      int cl = wc + sc * 16 + l15;
      int c = c0 + cl;
      float bia = bq[c] + ((p == 0) ? cbv[c] : pbv[c]);
      #pragma unroll
      for (int sr = 0; sr < 2; ++sr)
        #pragma unroll
        for (int r = 0; r < 4; ++r) {
          int ml = wm + sr * 16 + quad * 4 + r;
          LDb[ml * 72 + cl] = f2b((accq[sr][sc][r] + bia) * 0.125f);
        }
    }
    __syncthreads();
    int row = t >> 2;
    unsigned short* C = (p == 0) ? qcb : qpb;
    #pragma unroll
    for (int j = 0; j < 2; ++j) {
      int col = (t & 3) * 16 + j * 8;
      int4 val = *(const int4*)(LDb + row * 72 + col);
      int c = c0 + col, n = c >> 6, d = c & 63;
      int m = r0 + row, bb = m >> 11, l = m & 2047;
      *(int4*)(C + ((size_t)(bb * NH + n) * LSEQ + l) * DH + d) = val;
    }
  }

  __syncthreads();
  #pragma unroll
  for (int sc = 0; sc < 2; ++sc) {
    int cl = wc + sc * 16 + l15;
    float bia = bk[c0 + cl];
    #pragma unroll
    for (int sr = 0; sr < 2; ++sr)
      #pragma unroll
      for (int r = 0; r < 4; ++r) {
        int ml = wm + sr * 16 + quad * 4 + r;
        LDb[ml * 72 + cl] = f2b(acck[sr][sc][r] + bia);
      }
  }
  __syncthreads();
  {
    int row = t >> 2;
    #pragma unroll
    for (int j = 0; j < 2; ++j) {
      int col = (t & 3) * 16 + j * 8;
      int4 val = *(const int4*)(LDb + row * 72 + col);
      int c = c0 + col, n = c >> 6, d = c & 63;
      int m = r0 + row, bb = m >> 11, l = m & 2047;
      *(int4*)(kbb + ((size_t)(bb * NH + n) * LSEQ + l) * DH + d) = val;
    }
  }

  __syncthreads();
  #pragma unroll
  for (int sc = 0; sc < 2; ++sc) {
    int cl = wc + sc * 16 + l15;
    float bia = bv[c0 + cl];
    #pragma unroll
    for (int sr = 0; sr < 2; ++sr)
      #pragma unroll
      for (int r = 0; r < 4; ++r) {
        int ml = wm + sr * 16 + quad * 4 + r;
        LDb[cl * 72 + ml] = f2b(accv[sr][sc][r] + bia);
      }
  }
  __syncthreads();
  {
    int row = t >> 2;                 // c-local
    int c = c0 + row, n = c >> 6, d = c & 63;
    #pragma unroll
    for (int j = 0; j < 2; ++j) {
      int mcol = (t & 3) * 16 + j * 8;
      int4 val = *(const int4*)(LDb + row * 72 + mcol);
      int m = r0 + mcol, bb = m >> 11, l = m & 2047;
      *(int4*)(vtb + ((size_t)(bb * NH + n) * DH + d) * LSEQ + l) = val;
    }
  }
}

// ---------------------------------------------------------------------------
// MFMA flash attention. R14: Res band RING BUFFER — the band shifts by -64
// rows per j-tile (dist_next(r) = dist_cur(r-64)), so rows 64..127 carry
// over; each tile after the first loads only 64 new rows (logical 0..63).
// phys(r) = (r + off) & 127, off += 64 per tile (off % 4 == 0 keeps the
// row&3 XOR swizzle invariant). Rest is the R7-proven body.
// ---------------------------------------------------------------------------
#define PROW(i) ((i) * 72 + (((i) >> 2) << 3))

__global__ __launch_bounds__(256, 3) void attn_mfma(
    const unsigned short* __restrict__ qcb, const unsigned short* __restrict__ qpb,
    const unsigned short* __restrict__ kbb, const unsigned short* __restrict__ vtb,
    const unsigned short* __restrict__ rebb, unsigned short* __restrict__ outb)
{
  __shared__ __align__(16) unsigned short Ks[64 * 72];
  __shared__ __align__(16) unsigned short Vts[64 * 72];
  __shared__ __align__(16) unsigned short Res[128 * 72];
  __shared__ __align__(16) unsigned short TPb[4 * 16 * 84];

  const int t = threadIdx.x;
  const int bn = blockIdx.x;
  const int b = bn >> 3, n = bn & 7;
  const int ib = 31 - blockIdx.y;
  const int i0 = ib * 64;
  const int w = t >> 6;
  const int lane = t & 63;
  const int l15 = lane & 15, quad = lane >> 4;

  bf16x8 qcf[2], qpf[2];
  {
    size_t base = ((size_t)bn * LSEQ + i0 + 16 * w + l15) * DH + quad * 8;
    qcf[0] = *(const bf16x8*)(qcb + base);
    qcf[1] = *(const bf16x8*)(qcb + base + 32);
    qpf[0] = *(const bf16x8*)(qpb + base);
    qpf[1] = *(const bf16x8*)(qpb + base + 32);
  }

  f32x4 Of[4];
  #pragma unroll
  for (int s = 0; s < 4; ++s) Of[s] = (f32x4){0.f, 0.f, 0.f, 0.f};
  float lsum[4] = {0.f, 0.f, 0.f, 0.f};

  unsigned short* Tw = TPb + w * 1344;
  const int Ibase = i0 + 16 * w;
  const int nt = ib + 1;

  const int r2 = t >> 2, gl2 = t & 3;
  const int r1 = t >> 1, h1 = t & 1;

  int roff = 0;    // Res ring offset (phys = (logical + roff) & 127)

  for (int tt = 0; tt < nt; ++tt) {
    const int j0 = tt * 64;
    const int db = i0 - j0;

    // ---- prefetch K/V (full) and Res (full at tt=0, else 64 new rows) ----
    const int4* skp = (const int4*)(kbb + ((size_t)bn * LSEQ + j0 + r2) * DH + gl2 * 16);
    int4 ka0 = skp[0], ka1 = skp[1];
    const int4* svp = (const int4*)(vtb + ((size_t)bn * DH + r2) * LSEQ + j0 + gl2 * 16);
    int4 va0 = svp[0], va1 = svp[1];

    int4 ra[2][2];
    int4 rn0, rn1;
    if (tt == 0) {
      int dist = db - 63 + r1;
      #pragma unroll
      for (int gi = 0; gi < 2; ++gi) {
        if (dist >= 0 && dist < LSEQ) {
          const int4* srp = (const int4*)(rebb + ((size_t)n * LSEQ + dist) * DH + (h1 * 2 + gi) * 16);
          ra[gi][0] = srp[0]; ra[gi][1] = srp[1];
        } else {
          int4 z = {0, 0, 0, 0};
          ra[gi][0] = z; ra[gi][1] = z;
        }
      }
    } else {
      int dist = db - 63 + r2;    // logical rows 0..63 are the new ones
      if (dist >= 0 && dist < LSEQ) {
        const int4* srp = (const int4*)(rebb + ((size_t)n * LSEQ + dist) * DH + gl2 * 16);
        rn0 = srp[0]; rn1 = srp[1];
      } else {
        int4 z = {0, 0, 0, 0};
        rn0 = z; rn1 = z;
      }
    }
    __syncthreads();   // previous tile's LDS reads complete
    {
      unsigned short* dk = Ks + r2 * 72 + ((gl2 ^ (r2 & 3)) * 16);
      *(int4*)(dk) = ka0; *(int4*)(dk + 8) = ka1;
      unsigned short* dv = Vts + r2 * 72 + ((gl2 ^ (r2 & 3)) * 16);
      *(int4*)(dv) = va0; *(int4*)(dv + 8) = va1;
      if (tt == 0) {
        #pragma unroll
        for (int gi = 0; gi < 2; ++gi) {
          int gl = h1 * 2 + gi;
          unsigned short* dr = Res + r1 * 72 + ((gl ^ (r1 & 3)) * 16);
          *(int4*)(dr) = ra[gi][0]; *(int4*)(dr + 8) = ra[gi][1];
        }
      } else {
        int p = (r2 + roff) & 127;
        unsigned short* dr = Res + p * 72 + ((gl2 ^ (p & 3)) * 16);
        *(int4*)(dr) = rn0; *(int4*)(dr + 8) = rn1;
      }
    }
    __syncthreads();

    // ---- content scores ----
    f32x4 Sf[4];
    #pragma unroll
    for (int s = 0; s < 4; ++s) {
      f32x4 acc = {0.f, 0.f, 0.f, 0.f};
      int row = 16 * s + l15;
      #pragma unroll
      for (int kk = 0; kk < 2; ++kk) {
        int g = (quad >> 1) + 2 * kk;
        bf16x8 bfr = *(const bf16x8*)(Ks + row * 72 + ((g ^ (row & 3)) * 16) + (quad & 1) * 8);
        acc = __builtin_amdgcn_mfma_f32_16x16x32_bf16(qcf[kk], bfr, acc, 0, 0, 0);
      }
      Sf[s] = acc;
    }
    // ---- positional T: Res read through the ring ----
    #pragma unroll
    for (int s = 0; s < 5; ++s) {
      f32x4 acc = {0.f, 0.f, 0.f, 0.f};
      int rlog = 16 * w + 16 * s + l15;
      int rp = (rlog + roff) & 127;
      #pragma unroll
      for (int kk = 0; kk < 2; ++kk) {
        int g = (quad >> 1) + 2 * kk;
        bf16x8 bfr = *(const bf16x8*)(Res + rp * 72 + ((g ^ (rp & 3)) * 16) + (quad & 1) * 8);
        acc = __builtin_amdgcn_mfma_f32_16x16x32_bf16(qpf[kk], bfr, acc, 0, 0, 0);
      }
      #pragma unroll
      for (int r = 0; r < 4; ++r) {
        int i = quad * 4 + r;
        Tw[i * 84 + 16 * s + l15] = f2b(acc[r]);
      }
    }
    asm volatile("s_waitcnt lgkmcnt(0)" ::: "memory");

    // ---- max-free softmax ----
    float p_s[4][4];
    #pragma unroll
    for (int s = 0; s < 4; ++s)
      #pragma unroll
      for (int r = 0; r < 4; ++r) {
        int i = quad * 4 + r;
        float tval = b2f(Tw[i * 84 + 63 + i - 16 * s - l15]);
        float v = Sf[s][r] + tval;
        int j = j0 + 16 * s + l15;
        float p = (j <= Ibase + i) ? __expf(v) : 0.0f;
        p_s[s][r] = p;
        lsum[r] += p;
      }
    #pragma unroll
    for (int s = 0; s < 4; ++s)
      #pragma unroll
      for (int r = 0; r < 4; ++r) {
        int i = quad * 4 + r;
        Tw[PROW(i) + ((s ^ (i & 3)) * 16) + l15] = f2b(p_s[s][r]);
      }
    asm volatile("s_waitcnt lgkmcnt(0)" ::: "memory");

    // ---- PV ----
    #pragma unroll
    for (int kk = 0; kk < 2; ++kk) {
      int g = (quad >> 1) + 2 * kk;
      bf16x8 pa = *(const bf16x8*)(Tw + PROW(l15) + ((g ^ (l15 & 3)) * 16) + (quad & 1) * 8);
      #pragma unroll
      for (int s = 0; s < 4; ++s) {
        int d = 16 * s + l15;
        bf16x8 vb8 = *(const bf16x8*)(Vts + d * 72 + ((g ^ (d & 3)) * 16) + (quad & 1) * 8);
        Of[s] = __builtin_amdgcn_mfma_f32_16x16x32_bf16(pa, vb8, Of[s], 0, 0, 0);
      }
    }
    roff = (roff + 64) & 127;
  }

  #pragma unroll
  for (int r = 0; r < 4; ++r) {
    float rs = lsum[r];
    rs += __shfl_xor(rs, 1, 64);
    rs += __shfl_xor(rs, 2, 64);
    rs += __shfl_xor(rs, 4, 64);
    rs += __shfl_xor(rs, 8, 64);
    float linv = 1.0f / rs;
    int I = Ibase + quad * 4 + r;
    size_t base = ((size_t)b * LSEQ + I) * HDIM + n * DH;
    #pragma unroll
    for (int s = 0; s < 4; ++s)
      outb[base + 16 * s + l15] = f2b(Of[s][r] * linv);
  }
}

// ---------------------------------------------------------------------------
// LayerNorm, bf16 input, one wave per row (4 rows/block), shuffle-only.
// ---------------------------------------------------------------------------
__global__ __launch_bounds__(256) void ln_b16(
    const unsigned short* __restrict__ xin, const float* __restrict__ w,
    const float* __restrict__ bb, float* __restrict__ outf,
    unsigned short* __restrict__ out16)
{
  const int t = threadIdx.x;
  const int lane = t & 63;
  const int row = blockIdx.x * 4 + (t >> 6);
  const size_t base = (size_t)row * 512 + lane * 8;

  unsigned short v16[8];
  *(int4*)v16 = *(const int4*)(xin + base);
  float v[8];
  float s = 0.f;
  #pragma unroll
  for (int i = 0; i < 8; ++i) { v[i] = b2f(v16[i]); s += v[i]; }
  #pragma unroll
  for (int off = 32; off >= 1; off >>= 1) s += __shfl_xor(s, off, 64);
  float mean = s * (1.0f / 512.0f);
  float s2 = 0.f;
  #pragma unroll
  for (int i = 0; i < 8; ++i) { float d = v[i] - mean; s2 += d * d; }
  #pragma unroll
  for (int off = 32; off >= 1; off >>= 1) s2 += __shfl_xor(s2, off, 64);
  float inv = 1.0f / sqrtf(s2 * (1.0f / 512.0f) + 1e-12f);

  float4 wa = *(const float4*)(w + lane * 8);
  float4 wb = *(const float4*)(w + lane * 8 + 4);
  float4 ba = *(const float4*)(bb + lane * 8);
  float4 bbv = *(const float4*)(bb + lane * 8 + 4);
  float o[8];
  o[0] = wa.x * (v[0] - mean) * inv + ba.x;
  o[1] = wa.y * (v[1] - mean) * inv + ba.y;
  o[2] = wa.z * (v[2] - mean) * inv + ba.z;
  o[3] = wa.w * (v[3] - mean) * inv + ba.w;
  o[4] = wb.x * (v[4] - mean) * inv + bbv.x;
  o[5] = wb.y * (v[5] - mean) * inv + bbv.y;
  o[6] = wb.z * (v[6] - mean) * inv + bbv.z;
  o[7] = wb.w * (v[7] - mean) * inv + bbv.w;
  if (outf) {
    float4 f0 = {o[0], o[1], o[2], o[3]}, f1 = {o[4], o[5], o[6], o[7]};
    *(float4*)(outf + base) = f0;
    *(float4*)(outf + base + 4) = f1;
  }
  if (out16) {
    unsigned short u[8];
    #pragma unroll
    for (int i = 0; i < 8; ++i) u[i] = f2b(o[i]);
    *(int4*)(out16 + base) = *(int4*)u;
  }
}

// ---------------------------------------------------------------------------
extern "C" void kernel_launch(void* const* d_in, const int* in_sizes, int n_in,
                              void* d_out, int out_size, void* d_ws, size_t ws_size,
                              hipStream_t stream)
{
  (void)in_sizes; (void)n_in; (void)out_size; (void)ws_size;
  const float* x   = (const float*)d_in[0];
  const float* pos = (const float*)d_in[1];
  const float* Wq  = (const float*)d_in[2];
  const float* bq  = (const float*)d_in[3];
  const float* Wk  = (const float*)d_in[4];
  const float* bk  = (const float*)d_in[5];
  const float* Wv  = (const float*)d_in[6];
  const float* bv  = (const float*)d_in[7];
  const float* Wr  = (const float*)d_in[8];
  const float* br  = (const float*)d_in[9];
  const float* cbv = (const float*)d_in[10];
  const float* pbv = (const float*)d_in[11];
  const float* Wc  = (const float*)d_in[12];
  const float* bc  = (const float*)d_in[13];
  const float* W1  = (const float*)d_in[14];
  const float* b1  = (const float*)d_in[15];
  const float* W2  = (const float*)d_in[16];
  const float* b2  = (const float*)d_in[17];
  const float* lnw = (const float*)d_in[18];
  const float* lnb = (const float*)d_in[19];
  char* ws = (char*)d_ws;
  float* outp = (float*)d_out;

  unsigned short* xb   = (unsigned short*)(ws);
  unsigned short* posb = (unsigned short*)(ws + 8388608);
  unsigned short* wT   = (unsigned short*)(ws + 10485760);
  unsigned short* qcb  = (unsigned short*)(ws + 14155776);
  unsigned short* qpb  = (unsigned short*)(ws + 22544384);
  unsigned short* kbb  = (unsigned short*)(ws + 30932992);
  unsigned short* vtb  = (unsigned short*)(ws + 39321600);
  unsigned short* rebb = (unsigned short*)(ws + 47710208);
  unsigned short* WcT = wT + 4 * 262144;
  unsigned short* W1T = wT + 5 * 262144;
  unsigned short* W2T = wT + 6 * 262144;
  unsigned short* attnb  = (unsigned short*)d_out;
  unsigned short* cpre16 = (unsigned short*)(ws + 14155776);  // over qcb
  unsigned short* ab16   = (unsigned short*)(ws);             // over xb
  unsigned short* h1b    = (unsigned short*)(ws + 30932992);  // over kbb
  unsigned short* h2b16  = (unsigned short*)(ws + 22544384);  // over qpb

  dim3 blk(256);
  dim3 g8(8, 128);   // M=8192: 64x64 tiles -> 1024 blocks (4/CU)

  conv_all<<<dim3(4096, 1, 3), blk, 0, stream>>>(
      x, pos, Wq, Wk, Wv, Wr, Wc, W1, W2, xb, posb, wT);

  qkv3<<<dim3(8, 128, 2), blk, 0, stream>>>(
      xb, posb, wT, bq, bk, bv, br, cbv, pbv, qcb, qpb, kbb, vtb, rebb);

  attn_mfma<<<dim3(32, 32), blk, 0, stream>>>(qcb, qpb, kbb, vtb, rebb, attnb);

  gemm_mfma<<<g8, blk, 0, stream>>>(attnb, WcT, bc, x, nullptr, cpre16, MODE_B16RES);
  ln_b16<<<2048, blk, 0, stream>>>(cpre16, lnw, lnb, nullptr, ab16);
  gemm_mfma<<<g8, blk, 0, stream>>>(ab16, W1T, b1, nullptr, nullptr, h1b, MODE_GELU);
  gemm_mfma<<<g8, blk, 0, stream>>>(h1b, W2T, b2, nullptr, ab16, h2b16, MODE_B16RES);
  ln_b16<<<2048, blk, 0, stream>>>(h2b16, lnw, lnb, outp, nullptr);
}